// Round 6
// baseline (10846.272 us; speedup 1.0000x reference)
//
#include <hip/hip_runtime.h>

// PositionCloser round 19: R15 base + gates g,o on FULL-RATE VALU fma_mix.
// R18 post-mortem: 1390 cyc/step = 256 MFMA (MfmaUtil 18.7% exact) + 865
// VALU -> v_dot2_f32_f16 is QUARTER-RATE (~8cyc) on gfx950 (also explains
// R13's 1000-cyc steps: 128 dot2 ~ 1024 cyc). Same split, right instrument:
// v_fma_mix_f32 (full-rate, f16 srcs, f32 accum). Gates i,f = 16 MFMAs
// (256 pipe cyc, tiles 0..7, R15-verified mapping); gates g,o = 128 fma_mix
// (256 VALU cyc, 8 interleaved acc chains) with 32 uniform ds_bpermute
// h-pairs (DS pipe) + packed-f16 weights in VGPRs. fma_mix chunks are
// source-interleaved between independent MFMAs so the in-order wave issues
// VALU inside the matrix-pipe shadow -> the two 256-cyc costs overlap.
// Shell/sync/loss identical to R15 (absmax 0.0 proven).

#define CH  128
#define HID 64

typedef __fp16 half8 __attribute__((ext_vector_type(8)));
typedef float  f32x4 __attribute__((ext_vector_type(4)));
typedef int    int4v __attribute__((ext_vector_type(4)));

__device__ __forceinline__ float rlf(float v, int l) {
  return __builtin_bit_cast(float, __builtin_amdgcn_readlane(__builtin_bit_cast(int, v), l));
}
__device__ __forceinline__ int packh(float a, float b) {
  return __builtin_bit_cast(int, __builtin_amdgcn_cvt_pkrtz(a, b));
}
__device__ __forceinline__ float frcp(float x) { return __builtin_amdgcn_rcpf(x); }
__device__ __forceinline__ float sigm(float x) { return frcp(1.0f + __expf(-x)); }
__device__ __forceinline__ float tanh_(float x) {
  float e = __expf(2.0f * x);
  return 1.0f - 2.0f * frcp(e + 1.0f);
}
template <int CTRL, int RMASK>
__device__ __forceinline__ float dpp_add(float v) {
  int x = __builtin_amdgcn_update_dpp(0, __builtin_bit_cast(int, v), CTRL, RMASK, 0xF, true);
  return v + __builtin_bit_cast(float, x);
}
__device__ __forceinline__ float dpp_xor1(float v) {  // quad_perm [1,0,3,2]
  int x = __builtin_amdgcn_update_dpp(0, __builtin_bit_cast(int, v), 0xB1, 0xF, 0xF, true);
  return __builtin_bit_cast(float, x);
}
__device__ __forceinline__ float dpp_wave_sum(float v) {  // total lands in lane 63
  v = dpp_add<0x111, 0xF>(v);
  v = dpp_add<0x112, 0xF>(v);
  v = dpp_add<0x114, 0xF>(v);
  v = dpp_add<0x118, 0xF>(v);
  v = dpp_add<0x142, 0xA>(v);   // row_bcast:15
  v = dpp_add<0x143, 0xC>(v);   // row_bcast:31
  return v;
}

// 16 full-rate mixed FMAs: 4 h-pairs x {lo,hi} x gates {g,o}, 8 acc chains.
// lo: op_sel default; hi: op_sel:[1,1,0]. src2/dst f32 (op_sel_hi[2]=0).
#define MIX16(HB0, HB1, HB2, HB3, P) asm( \
  "v_fma_mix_f32 %[g0], %[h0], %[wg0], %[g0] op_sel_hi:[1,1,0]\n\t" \
  "v_fma_mix_f32 %[o0], %[h0], %[wo0], %[o0] op_sel_hi:[1,1,0]\n\t" \
  "v_fma_mix_f32 %[g1], %[h0], %[wg0], %[g1] op_sel:[1,1,0] op_sel_hi:[1,1,0]\n\t" \
  "v_fma_mix_f32 %[o1], %[h0], %[wo0], %[o1] op_sel:[1,1,0] op_sel_hi:[1,1,0]\n\t" \
  "v_fma_mix_f32 %[g2], %[h1], %[wg1], %[g2] op_sel_hi:[1,1,0]\n\t" \
  "v_fma_mix_f32 %[o2], %[h1], %[wo1], %[o2] op_sel_hi:[1,1,0]\n\t" \
  "v_fma_mix_f32 %[g3], %[h1], %[wg1], %[g3] op_sel:[1,1,0] op_sel_hi:[1,1,0]\n\t" \
  "v_fma_mix_f32 %[o3], %[h1], %[wo1], %[o3] op_sel:[1,1,0] op_sel_hi:[1,1,0]\n\t" \
  "v_fma_mix_f32 %[g0], %[h2], %[wg2], %[g0] op_sel_hi:[1,1,0]\n\t" \
  "v_fma_mix_f32 %[o0], %[h2], %[wo2], %[o0] op_sel_hi:[1,1,0]\n\t" \
  "v_fma_mix_f32 %[g1], %[h2], %[wg2], %[g1] op_sel:[1,1,0] op_sel_hi:[1,1,0]\n\t" \
  "v_fma_mix_f32 %[o1], %[h2], %[wo2], %[o1] op_sel:[1,1,0] op_sel_hi:[1,1,0]\n\t" \
  "v_fma_mix_f32 %[g2], %[h3], %[wg3], %[g2] op_sel_hi:[1,1,0]\n\t" \
  "v_fma_mix_f32 %[o2], %[h3], %[wo3], %[o2] op_sel_hi:[1,1,0]\n\t" \
  "v_fma_mix_f32 %[g3], %[h3], %[wg3], %[g3] op_sel:[1,1,0] op_sel_hi:[1,1,0]\n\t" \
  "v_fma_mix_f32 %[o3], %[h3], %[wo3], %[o3] op_sel:[1,1,0] op_sel_hi:[1,1,0]" \
  : [g0] "+v"(g0), [g1] "+v"(g1), [g2] "+v"(g2), [g3] "+v"(g3), \
    [o0] "+v"(o0), [o1] "+v"(o1), [o2] "+v"(o2), [o3] "+v"(o3) \
  : [h0] "v"(HB0), [h1] "v"(HB1), [h2] "v"(HB2), [h3] "v"(HB3), \
    [wg0] "v"(Wg[4 * P + 0]), [wg1] "v"(Wg[4 * P + 1]), \
    [wg2] "v"(Wg[4 * P + 2]), [wg3] "v"(Wg[4 * P + 3]), \
    [wo0] "v"(Wo[4 * P + 0]), [wo1] "v"(Wo[4 * P + 1]), \
    [wo2] "v"(Wo[4 * P + 2]), [wo3] "v"(Wo[4 * P + 3]))

__global__ __attribute__((amdgpu_flat_work_group_size(128, 128), amdgpu_waves_per_eu(2, 2)))
void pc_lstm_kernel(const int* __restrict__ inds,
                    const float* __restrict__ p,
                    const float* __restrict__ ls_probs,
                    const float* __restrict__ open_probs,
                    const int* __restrict__ open_slices,
                    const float* __restrict__ open_hx,
                    const float* __restrict__ W_ih,
                    const float* __restrict__ W_hh,
                    const float* __restrict__ b_ih,
                    const float* __restrict__ b_hh,
                    const float* __restrict__ W_out,
                    const float* __restrict__ b_out,
                    const int* __restrict__ n_chunks_p,
                    float* __restrict__ out)
{
  __shared__ __fp16 ring[2][CH][HID];   // 32 KB: h history for the lagged loss
  __shared__ int prod;                  // chunks fully written by wave0
  __shared__ int cons;                  // chunks fully consumed by wave1

  const int tid  = threadIdx.x;
  const int wv   = tid >> 6;           // 0 = compute, 1 = loss
  const int lane = tid & 63;
  const int s    = blockIdx.x;         // one sequence per block
  const int n_chunks = n_chunks_p[0];
  const int tbase = inds[s >> 4] + (s & 15);
  const float2* p2 = (const float2*)p;

  if (tid == 0) { prod = 0; cons = 0; }
  __syncthreads();                      // only barrier in the kernel

  if (wv == 0) {
    // ================= compute wave =================
    const int kg = lane >> 4;          // k-group (A/B fragment k-chunk index)
    const int cc = lane & 15;          // column within a 16-wide N-tile

    // MFMA B fragments for gates i,f (tiles 0..7; HW-verified packing):
    // tile t covers preact rows n = 16t + col; k = 32*kc + 8*kg + j.
    half8 Wb[16];
#pragma unroll
    for (int t = 0; t < 8; ++t) {
#pragma unroll
      for (int kc = 0; kc < 2; ++kc) {
        const float* wp = W_hh + (16 * t + cc) * HID + 32 * kc + 8 * kg;
        half8 w;
#pragma unroll
        for (int j = 0; j < 8; ++j) w[j] = (__fp16)wp[j];
        Wb[2 * t + kc] = w;
      }
    }

    // fma_mix weights for gates g,o: lane owns row hid=lane, packed f16 pairs.
    int Wg[32], Wo[32];
    {
      const float2* rg = (const float2*)(W_hh + (2 * HID + lane) * HID);
      const float2* ro = (const float2*)(W_hh + (3 * HID + lane) * HID);
#pragma unroll
      for (int j = 0; j < 32; ++j) {
        float2 vg = rg[j], vo = ro[j];
        Wg[j] = packh(vg.x, vg.y);
        Wo[j] = packh(vo.x, vo.y);
      }
    }

    float wxa[4], wxb[4], bb[4];
#pragma unroll
    for (int g = 0; g < 4; ++g) {
      const int r = g * HID + lane;
      wxa[g] = W_ih[2 * r];
      wxb[g] = W_ih[2 * r + 1];
      bb[g]  = b_ih[r] + b_hh[r];
    }
    float h = open_hx[(s * 2 + 0) * HID + lane];
    float c = open_hx[(s * 2 + 1) * HID + lane];

    // bpermute byte-indices (loop-invariant):
    // A-frags: a0 word w pulls hp from lane 8*kg+2w; a1 from lane 32+8*kg+2w.
    int ia0[4], ia1[4];
#pragma unroll
    for (int w = 0; w < 4; ++w) {
      ia0[w] = 4 * (8 * kg + 2 * w);
      ia1[w] = 4 * (32 + 8 * kg + 2 * w);
    }

    const bool u1 = (lane & 16) != 0;  // bit0 of u = lane>>4
    const bool u2 = (lane & 32) != 0;  // bit1 of u
    const f32x4 zero4 = {0.f, 0.f, 0.f, 0.f};

    float2 curA = p2[tbase + lane];
    float2 curB = p2[tbase + HID + lane];
    float2 nxtA = curA, nxtB = curB;

    for (int off = 0; off < n_chunks; ++off) {
      if (off) { curA = nxtA; curB = nxtB; }
      const float px0 = rlf(curA.x, 0);
      const float px1 = rlf(curA.y, 0);
      float2 xA, xB;                       // pre-subtracted chunk base
      xA.x = curA.x - px0; xA.y = curA.y - px1;
      xB.x = curB.x - px0; xB.y = curB.y - px1;
      if (off + 1 < n_chunks) {
        const int nb = tbase + (off + 1) * CH;
        nxtA = p2[nb + lane];
        nxtB = p2[nb + HID + lane];
      }
      while (__hip_atomic_load(&cons, __ATOMIC_ACQUIRE, __HIP_MEMORY_SCOPE_WORKGROUP) + 2 <= off)
        __builtin_amdgcn_s_sleep(8);

      __fp16* slot = &ring[off & 1][0][0];
#pragma unroll
      for (int hf = 0; hf < 2; ++hf) {
        const float xcx = hf ? xB.x : xA.x;
        const float xcy = hf ? xB.y : xA.y;
#pragma unroll 1
        for (int tl = 0; tl < 64; ++tl) {
          // ---- packed h pairs (even lane 2j holds (h_2j, h_2j+1)) ----
          const int hp = packh(h, dpp_xor1(h));

          // ---- MFMA A fragments via crossbar ----
          int4v A0, A1;
#pragma unroll
          for (int w = 0; w < 4; ++w) {
            A0[w] = __builtin_amdgcn_ds_bpermute(ia0[w], hp);
            A1[w] = __builtin_amdgcn_ds_bpermute(ia1[w], hp);
          }
          const half8 a0 = __builtin_bit_cast(half8, A0);   // k = 0..31
          const half8 a1 = __builtin_bit_cast(half8, A1);   // k = 32..63

          const float x0 = rlf(xcx, tl);
          const float x1 = rlf(xcy, tl);

          // ---- g,o accumulators (8 chains, f32) ----
          float g0 = fmaf(x0, wxa[2], bb[2]);
          float g1 = x1 * wxb[2];
          float g2 = 0.0f, g3 = 0.0f;
          float o0 = fmaf(x0, wxa[3], bb[3]);
          float o1 = x1 * wxb[3];
          float o2 = 0.0f, o3 = 0.0f;

          // ---- interleaved: 16 MFMA (i,f) + 8x MIX16 (g,o) ----
          // first 8 MFMAs are the independent a0-stage; mixes fill the shadow
          f32x4 q0, q1, q2, q3, r0, r1, r2, r3;
          {
            const int hb0 = __builtin_amdgcn_ds_bpermute(8 * 0,  hp);
            const int hb1 = __builtin_amdgcn_ds_bpermute(8 * 1,  hp);
            const int hb2 = __builtin_amdgcn_ds_bpermute(8 * 2,  hp);
            const int hb3 = __builtin_amdgcn_ds_bpermute(8 * 3,  hp);
            q0 = __builtin_amdgcn_mfma_f32_16x16x32_f16(a0, Wb[0],  zero4, 0, 0, 0);
            q1 = __builtin_amdgcn_mfma_f32_16x16x32_f16(a0, Wb[2],  zero4, 0, 0, 0);
            MIX16(hb0, hb1, hb2, hb3, 0);
          }
          {
            const int hb0 = __builtin_amdgcn_ds_bpermute(8 * 4,  hp);
            const int hb1 = __builtin_amdgcn_ds_bpermute(8 * 5,  hp);
            const int hb2 = __builtin_amdgcn_ds_bpermute(8 * 6,  hp);
            const int hb3 = __builtin_amdgcn_ds_bpermute(8 * 7,  hp);
            q2 = __builtin_amdgcn_mfma_f32_16x16x32_f16(a0, Wb[4],  zero4, 0, 0, 0);
            q3 = __builtin_amdgcn_mfma_f32_16x16x32_f16(a0, Wb[6],  zero4, 0, 0, 0);
            MIX16(hb0, hb1, hb2, hb3, 1);
          }
          {
            const int hb0 = __builtin_amdgcn_ds_bpermute(8 * 8,  hp);
            const int hb1 = __builtin_amdgcn_ds_bpermute(8 * 9,  hp);
            const int hb2 = __builtin_amdgcn_ds_bpermute(8 * 10, hp);
            const int hb3 = __builtin_amdgcn_ds_bpermute(8 * 11, hp);
            r0 = __builtin_amdgcn_mfma_f32_16x16x32_f16(a0, Wb[8],  zero4, 0, 0, 0);
            r1 = __builtin_amdgcn_mfma_f32_16x16x32_f16(a0, Wb[10], zero4, 0, 0, 0);
            MIX16(hb0, hb1, hb2, hb3, 2);
          }
          {
            const int hb0 = __builtin_amdgcn_ds_bpermute(8 * 12, hp);
            const int hb1 = __builtin_amdgcn_ds_bpermute(8 * 13, hp);
            const int hb2 = __builtin_amdgcn_ds_bpermute(8 * 14, hp);
            const int hb3 = __builtin_amdgcn_ds_bpermute(8 * 15, hp);
            r2 = __builtin_amdgcn_mfma_f32_16x16x32_f16(a0, Wb[12], zero4, 0, 0, 0);
            r3 = __builtin_amdgcn_mfma_f32_16x16x32_f16(a0, Wb[14], zero4, 0, 0, 0);
            MIX16(hb0, hb1, hb2, hb3, 3);
          }
          {
            const int hb0 = __builtin_amdgcn_ds_bpermute(8 * 16, hp);
            const int hb1 = __builtin_amdgcn_ds_bpermute(8 * 17, hp);
            const int hb2 = __builtin_amdgcn_ds_bpermute(8 * 18, hp);
            const int hb3 = __builtin_amdgcn_ds_bpermute(8 * 19, hp);
            q0 = __builtin_amdgcn_mfma_f32_16x16x32_f16(a1, Wb[1],  q0, 0, 0, 0);
            q1 = __builtin_amdgcn_mfma_f32_16x16x32_f16(a1, Wb[3],  q1, 0, 0, 0);
            MIX16(hb0, hb1, hb2, hb3, 4);
          }
          {
            const int hb0 = __builtin_amdgcn_ds_bpermute(8 * 20, hp);
            const int hb1 = __builtin_amdgcn_ds_bpermute(8 * 21, hp);
            const int hb2 = __builtin_amdgcn_ds_bpermute(8 * 22, hp);
            const int hb3 = __builtin_amdgcn_ds_bpermute(8 * 23, hp);
            q2 = __builtin_amdgcn_mfma_f32_16x16x32_f16(a1, Wb[5],  q2, 0, 0, 0);
            q3 = __builtin_amdgcn_mfma_f32_16x16x32_f16(a1, Wb[7],  q3, 0, 0, 0);
            MIX16(hb0, hb1, hb2, hb3, 5);
          }
          {
            const int hb0 = __builtin_amdgcn_ds_bpermute(8 * 24, hp);
            const int hb1 = __builtin_amdgcn_ds_bpermute(8 * 25, hp);
            const int hb2 = __builtin_amdgcn_ds_bpermute(8 * 26, hp);
            const int hb3 = __builtin_amdgcn_ds_bpermute(8 * 27, hp);
            r0 = __builtin_amdgcn_mfma_f32_16x16x32_f16(a1, Wb[9],  r0, 0, 0, 0);
            r1 = __builtin_amdgcn_mfma_f32_16x16x32_f16(a1, Wb[11], r1, 0, 0, 0);
            MIX16(hb0, hb1, hb2, hb3, 6);
          }
          {
            const int hb0 = __builtin_amdgcn_ds_bpermute(8 * 28, hp);
            const int hb1 = __builtin_amdgcn_ds_bpermute(8 * 29, hp);
            const int hb2 = __builtin_amdgcn_ds_bpermute(8 * 30, hp);
            const int hb3 = __builtin_amdgcn_ds_bpermute(8 * 31, hp);
            r2 = __builtin_amdgcn_mfma_f32_16x16x32_f16(a1, Wb[13], r2, 0, 0, 0);
            r3 = __builtin_amdgcn_mfma_f32_16x16x32_f16(a1, Wb[15], r3, 0, 0, 0);
            MIX16(hb0, hb1, hb2, hb3, 7);
          }

          // ---- extract i,f preacts (same select as R15, absmax-0 verified) ----
          const float si01 = u1 ? q1[0] : q0[0];
          const float si23 = u1 ? q3[0] : q2[0];
          const float di   = u2 ? si23 : si01;
          const float sf01 = u1 ? r1[0] : r0[0];
          const float sf23 = u1 ? r3[0] : r2[0];
          const float df   = u2 ? sf23 : sf01;
          const float pai = fmaf(x0, wxa[0], fmaf(x1, wxb[0], di + bb[0]));
          const float paf = fmaf(x0, wxa[1], fmaf(x1, wxb[1], df + bb[1]));

          const float ig = sigm(pai);
          const float fg = sigm(paf);
          const float gg = tanh_((g0 + g1) + (g2 + g3));
          const float og = sigm((o0 + o1) + (o2 + o3));
          c = fmaf(fg, c, ig * gg);
          h = og * tanh_(c);

          const int tt = hf * 64 + tl;
          slot[tt * HID + lane] = (__fp16)h;   // ds_write_b16 (ring, off chain)
        }
      }
      if (lane == 0)
        __hip_atomic_store(&prod, off + 1, __ATOMIC_RELEASE, __HIP_MEMORY_SCOPE_WORKGROUP);
    }
  } else {
    // ================= loss wave =================
    const float wo   = W_out[lane];
    const float bout = b_out[0];
    const int   os   = open_slices[s];
    const float OL   = __logf(p[2 * os]) + __logf(p[2 * os + 1]);
    const float coef = open_probs[s] * (2.0f * ls_probs[s] - 1.0f);

    float S = 1.0f, D = 1.0f, lsum = 0.0f, psum = 0.0f;

    for (int off = 0; off < n_chunks; ++off) {
      const int cb = tbase + off * CH;
      const float2 cA = p2[cb + lane];
      const float2 cB = p2[cb + HID + lane];
      const float LA = __logf(cA.x) + __logf(cA.y);
      const float LB = __logf(cB.x) + __logf(cB.y);

      while (__hip_atomic_load(&prod, __ATOMIC_ACQUIRE, __HIP_MEMORY_SCOPE_WORKGROUP) <= off)
        __builtin_amdgcn_s_sleep(32);

      const __fp16* slot = &ring[off & 1][0][0];
#pragma unroll 1
      for (int tt = 0; tt < CH; ++tt) {
        const float hv = (float)slot[tt * HID + lane];
        const float z  = rlf(dpp_wave_sum(hv * wo), 63);
        const float pr = sigm(z + bout);
        const float Lt = (tt < 64) ? rlf(LA, tt) : rlf(LB, tt - 64);
        const float pn = (tt == 0) ? pr : pr * D;
        lsum = fmaf(pn, Lt, lsum);
        psum += pn;
        if (tt == 0)           D = S * (1.0f - pr);   // chunk t=0 undiscounted (ref quirk)
        else if (tt < CH - 1)  D *= (1.0f - pr);
        else                   S = D;                  // carry excludes (1-p_last)
      }
      if (lane == 0)
        __hip_atomic_store(&cons, off + 1, __ATOMIC_RELEASE, __HIP_MEMORY_SCOPE_WORKGROUP);
    }
    if (lane == 0) atomicAdd(out, coef * (lsum - OL * psum));
  }
}

extern "C" void kernel_launch(void* const* d_in, const int* in_sizes, int n_in,
                              void* d_out, int out_size, void* d_ws, size_t ws_size,
                              hipStream_t stream) {
  (void)hipMemsetAsync(d_out, 0, sizeof(float), stream);

  pc_lstm_kernel<<<dim3(1024), dim3(128), 0, stream>>>(
      (const int*)d_in[0],    // inds
      (const float*)d_in[1],  // p
      (const float*)d_in[2],  // ls_probs
      (const float*)d_in[3],  // open_probs
      (const int*)d_in[4],    // open_slices
      (const float*)d_in[5],  // open_hx
      (const float*)d_in[6],  // W_ih
      (const float*)d_in[7],  // W_hh
      (const float*)d_in[8],  // b_ih
      (const float*)d_in[9],  // b_hh
      (const float*)d_in[10], // W_out
      (const float*)d_in[11], // b_out
      (const int*)d_in[12],   // n_chunks
      (float*)d_out);
}

// Round 7
// 10164.667 us; speedup vs baseline: 1.0671x; 1.0671x over previous
//
#include <hip/hip_runtime.h>

// PositionCloser round 20: 3 gates on MFMA + o-gate on FULL-RATE packed f32.
// Measured instrument rates (R13/R18/R19 all consistent): mixed-f16 VALU MACs
// (v_dot2_f32_f16, v_fma_mix_f32) are QUARTER-RATE (~8cyc) on gfx950; only
// plain f32 v_fma/fmac (and v_pk_fma_f32) are full-rate (m07). Single-wave
// MFMA = 16 cyc/instr (R15: 49.4% x 1030 = 512 exact).
// Design: i,f,g on MFMA (24 instr = 384 pipe cyc; per-gate-sequential order
// keeps ~20 live acc regs); o on v_pk_fma_f32 (32 instr, f32 weights = 64
// arch VGPRs, f32 accum). o's h operands via LDS scratch: ds_write_b32 +
// 16 uniform ds_read_b128 (broadcast, conflict-free, DS pipe) - all hidden
// under the MFMA shadow. i/f/g weights are MFMA-B AGPRs (96, free class).
// Mapping identical to R15 (absmax 0.0): tile T=4g+u holds gate g rows;
// acc[0] at lane = preact[16T + (lane&15)]. Shell/sync/loss = R15.

#define CH  128
#define HID 64

typedef __fp16 half8 __attribute__((ext_vector_type(8)));
typedef float  f32x4 __attribute__((ext_vector_type(4)));
typedef float  f32x2 __attribute__((ext_vector_type(2)));
typedef int    int4v __attribute__((ext_vector_type(4)));

__device__ __forceinline__ float rlf(float v, int l) {
  return __builtin_bit_cast(float, __builtin_amdgcn_readlane(__builtin_bit_cast(int, v), l));
}
__device__ __forceinline__ int packh(float a, float b) {
  return __builtin_bit_cast(int, __builtin_amdgcn_cvt_pkrtz(a, b));
}
__device__ __forceinline__ float frcp(float x) { return __builtin_amdgcn_rcpf(x); }
__device__ __forceinline__ float sigm(float x) { return frcp(1.0f + __expf(-x)); }
__device__ __forceinline__ float tanh_(float x) {
  float e = __expf(2.0f * x);
  return 1.0f - 2.0f * frcp(e + 1.0f);
}
template <int CTRL, int RMASK>
__device__ __forceinline__ float dpp_add(float v) {
  int x = __builtin_amdgcn_update_dpp(0, __builtin_bit_cast(int, v), CTRL, RMASK, 0xF, true);
  return v + __builtin_bit_cast(float, x);
}
__device__ __forceinline__ float dpp_xor1(float v) {  // quad_perm [1,0,3,2]
  int x = __builtin_amdgcn_update_dpp(0, __builtin_bit_cast(int, v), 0xB1, 0xF, 0xF, true);
  return __builtin_bit_cast(float, x);
}
__device__ __forceinline__ float dpp_wave_sum(float v) {  // total lands in lane 63
  v = dpp_add<0x111, 0xF>(v);
  v = dpp_add<0x112, 0xF>(v);
  v = dpp_add<0x114, 0xF>(v);
  v = dpp_add<0x118, 0xF>(v);
  v = dpp_add<0x142, 0xA>(v);   // row_bcast:15
  v = dpp_add<0x143, 0xC>(v);   // row_bcast:31
  return v;
}
// packed f32 FMA: acc.lo += a.lo*b.lo; acc.hi += a.hi*b.hi  (full-rate VOP3P)
__device__ __forceinline__ void pkfma(f32x2& acc, f32x2 a, f32x2 b) {
  asm("v_pk_fma_f32 %0, %1, %2, %0" : "+v"(acc) : "v"(a), "v"(b));
}

__global__ __attribute__((amdgpu_flat_work_group_size(128, 128), amdgpu_waves_per_eu(2, 2)))
void pc_lstm_kernel(const int* __restrict__ inds,
                    const float* __restrict__ p,
                    const float* __restrict__ ls_probs,
                    const float* __restrict__ open_probs,
                    const int* __restrict__ open_slices,
                    const float* __restrict__ open_hx,
                    const float* __restrict__ W_ih,
                    const float* __restrict__ W_hh,
                    const float* __restrict__ b_ih,
                    const float* __restrict__ b_hh,
                    const float* __restrict__ W_out,
                    const float* __restrict__ b_out,
                    const int* __restrict__ n_chunks_p,
                    float* __restrict__ out)
{
  __shared__ __fp16 ring[2][CH][HID];   // 32 KB: h history for the lagged loss
  __shared__ float  hbuf[HID];          // 256 B: f32 h scratch for the o-gate
  __shared__ int prod;                  // chunks fully written by wave0
  __shared__ int cons;                  // chunks fully consumed by wave1

  const int tid  = threadIdx.x;
  const int wv   = tid >> 6;           // 0 = compute, 1 = loss
  const int lane = tid & 63;
  const int s    = blockIdx.x;         // one sequence per block
  const int n_chunks = n_chunks_p[0];
  const int tbase = inds[s >> 4] + (s & 15);
  const float2* p2 = (const float2*)p;

  if (tid == 0) { prod = 0; cons = 0; }
  __syncthreads();                      // only barrier in the kernel

  if (wv == 0) {
    // ================= compute wave =================
    const int kg = lane >> 4;          // k-group (A/B fragment k-chunk index)
    const int cc = lane & 15;          // column within a 16-wide N-tile

    // MFMA B fragments for gates i,f,g (tiles 0..11; HW-verified packing):
    // frag idx = 8*gt + 2*tt + kc for tile T = 4*gt + tt, rows n = 16T + col,
    // k = 32*kc + 8*kg + j.
    half8 Wb[24];
#pragma unroll
    for (int gt = 0; gt < 3; ++gt) {
#pragma unroll
      for (int tt = 0; tt < 4; ++tt) {
#pragma unroll
        for (int kc = 0; kc < 2; ++kc) {
          const float* wp = W_hh + (16 * (4 * gt + tt) + cc) * HID + 32 * kc + 8 * kg;
          half8 w;
#pragma unroll
          for (int j = 0; j < 8; ++j) w[j] = (__fp16)wp[j];
          Wb[8 * gt + 2 * tt + kc] = w;
        }
      }
    }

    // o-gate weights: f32 pairs, lane owns row hid=lane (64 arch VGPRs).
    f32x2 wo2[32];
    {
      const f32x2* wrow = (const f32x2*)(W_hh + (3 * HID + lane) * HID);
#pragma unroll
      for (int j = 0; j < 32; ++j) wo2[j] = wrow[j];
    }

    float wxa[4], wxb[4], bb[4];
#pragma unroll
    for (int g = 0; g < 4; ++g) {
      const int r = g * HID + lane;
      wxa[g] = W_ih[2 * r];
      wxb[g] = W_ih[2 * r + 1];
      bb[g]  = b_ih[r] + b_hh[r];
    }
    float h = open_hx[(s * 2 + 0) * HID + lane];
    float c = open_hx[(s * 2 + 1) * HID + lane];

    // bpermute byte-indices (loop-invariant): a0 word w pulls hp from lane
    // 8*kg+2w; a1 from lane 32+8*kg+2w (+128 bytes folds into DS offset).
    int ia[4];
#pragma unroll
    for (int w = 0; w < 4; ++w) ia[w] = 4 * (8 * kg + 2 * w);

    const bool u1 = (lane & 16) != 0;  // bit0 of u = lane>>4
    const bool u2 = (lane & 32) != 0;  // bit1 of u
    const f32x4 zero4 = {0.f, 0.f, 0.f, 0.f};
    const f32x4* hb4 = (const f32x4*)hbuf;

    float2 curA = p2[tbase + lane];
    float2 curB = p2[tbase + HID + lane];
    float2 nxtA = curA, nxtB = curB;

#define OSTEP(J) { \
    const f32x4 h4 = hb4[J]; \
    pkfma(oacc0, __builtin_shufflevector(h4, h4, 0, 1), wo2[2 * (J)]); \
    pkfma(oacc1, __builtin_shufflevector(h4, h4, 2, 3), wo2[2 * (J) + 1]); }

    for (int off = 0; off < n_chunks; ++off) {
      if (off) { curA = nxtA; curB = nxtB; }
      const float px0 = rlf(curA.x, 0);
      const float px1 = rlf(curA.y, 0);
      float2 xA, xB;                       // pre-subtracted chunk base
      xA.x = curA.x - px0; xA.y = curA.y - px1;
      xB.x = curB.x - px0; xB.y = curB.y - px1;
      if (off + 1 < n_chunks) {
        const int nb = tbase + (off + 1) * CH;
        nxtA = p2[nb + lane];
        nxtB = p2[nb + HID + lane];
      }
      while (__hip_atomic_load(&cons, __ATOMIC_ACQUIRE, __HIP_MEMORY_SCOPE_WORKGROUP) + 2 <= off)
        __builtin_amdgcn_s_sleep(8);

      __fp16* slot = &ring[off & 1][0][0];
#pragma unroll
      for (int hf = 0; hf < 2; ++hf) {
        const float xcx = hf ? xB.x : xA.x;
        const float xcy = hf ? xB.y : xA.y;
#pragma unroll 1
        for (int tl = 0; tl < 64; ++tl) {
          // ---- head: h scratch + packed pairs + A fragments ----
          hbuf[lane] = h;                         // ds_write_b32 (f32 h)
          const int hp = packh(h, dpp_xor1(h));   // even lane 2j: (h_2j, h_2j+1)
          int4v A0, A1;
#pragma unroll
          for (int w = 0; w < 4; ++w) {
            A0[w] = __builtin_amdgcn_ds_bpermute(ia[w], hp);
            A1[w] = __builtin_amdgcn_ds_bpermute(ia[w] + 128, hp);
          }
          const half8 a0 = __builtin_bit_cast(half8, A0);   // k = 0..31
          const half8 a1 = __builtin_bit_cast(half8, A1);   // k = 32..63

          const float x0 = rlf(xcx, tl);
          const float x1 = rlf(xcy, tl);

          // o-gate accumulators (x-part + bias seeded)
          f32x2 oacc0, oacc1;
          oacc0[0] = fmaf(x0, wxa[3], bb[3]);
          oacc0[1] = x1 * wxb[3];
          oacc1[0] = 0.0f; oacc1[1] = 0.0f;

          // ---- g block (tiles 8..11, frags 16..23) + o pk j=0..7 ----
          f32x4 s0 = __builtin_amdgcn_mfma_f32_16x16x32_f16(a0, Wb[16], zero4, 0, 0, 0); OSTEP(0);
          f32x4 s1 = __builtin_amdgcn_mfma_f32_16x16x32_f16(a0, Wb[18], zero4, 0, 0, 0); OSTEP(1);
          f32x4 s2 = __builtin_amdgcn_mfma_f32_16x16x32_f16(a0, Wb[20], zero4, 0, 0, 0); OSTEP(2);
          f32x4 s3 = __builtin_amdgcn_mfma_f32_16x16x32_f16(a0, Wb[22], zero4, 0, 0, 0); OSTEP(3);
          s0 = __builtin_amdgcn_mfma_f32_16x16x32_f16(a1, Wb[17], s0, 0, 0, 0); OSTEP(4);
          s1 = __builtin_amdgcn_mfma_f32_16x16x32_f16(a1, Wb[19], s1, 0, 0, 0); OSTEP(5);
          s2 = __builtin_amdgcn_mfma_f32_16x16x32_f16(a1, Wb[21], s2, 0, 0, 0); OSTEP(6);
          s3 = __builtin_amdgcn_mfma_f32_16x16x32_f16(a1, Wb[23], s3, 0, 0, 0); OSTEP(7);
          const float sg01 = u1 ? s1[0] : s0[0];
          const float sg23 = u1 ? s3[0] : s2[0];
          const float dg   = u2 ? sg23 : sg01;
          const float pag  = fmaf(x0, wxa[2], fmaf(x1, wxb[2], dg + bb[2]));
          const float gg   = tanh_(pag);

          // ---- i block (tiles 0..3, frags 0..7) + o pk j=8..15 ----
          f32x4 q0 = __builtin_amdgcn_mfma_f32_16x16x32_f16(a0, Wb[0], zero4, 0, 0, 0); OSTEP(8);
          f32x4 q1 = __builtin_amdgcn_mfma_f32_16x16x32_f16(a0, Wb[2], zero4, 0, 0, 0); OSTEP(9);
          f32x4 q2 = __builtin_amdgcn_mfma_f32_16x16x32_f16(a0, Wb[4], zero4, 0, 0, 0); OSTEP(10);
          f32x4 q3 = __builtin_amdgcn_mfma_f32_16x16x32_f16(a0, Wb[6], zero4, 0, 0, 0); OSTEP(11);
          q0 = __builtin_amdgcn_mfma_f32_16x16x32_f16(a1, Wb[1], q0, 0, 0, 0); OSTEP(12);
          q1 = __builtin_amdgcn_mfma_f32_16x16x32_f16(a1, Wb[3], q1, 0, 0, 0); OSTEP(13);
          q2 = __builtin_amdgcn_mfma_f32_16x16x32_f16(a1, Wb[5], q2, 0, 0, 0); OSTEP(14);
          q3 = __builtin_amdgcn_mfma_f32_16x16x32_f16(a1, Wb[7], q3, 0, 0, 0); OSTEP(15);
          const float si01 = u1 ? q1[0] : q0[0];
          const float si23 = u1 ? q3[0] : q2[0];
          const float di   = u2 ? si23 : si01;
          const float pai  = fmaf(x0, wxa[0], fmaf(x1, wxb[0], di + bb[0]));
          const float ig   = sigm(pai);

          // ---- f block (tiles 4..7, frags 8..15) + o finish ----
          f32x4 r0 = __builtin_amdgcn_mfma_f32_16x16x32_f16(a0, Wb[8],  zero4, 0, 0, 0);
          f32x4 r1 = __builtin_amdgcn_mfma_f32_16x16x32_f16(a0, Wb[10], zero4, 0, 0, 0);
          const float osum = (oacc0[0] + oacc0[1]) + (oacc1[0] + oacc1[1]);
          f32x4 r2 = __builtin_amdgcn_mfma_f32_16x16x32_f16(a0, Wb[12], zero4, 0, 0, 0);
          const float og = sigm(osum);
          f32x4 r3 = __builtin_amdgcn_mfma_f32_16x16x32_f16(a0, Wb[14], zero4, 0, 0, 0);
          r0 = __builtin_amdgcn_mfma_f32_16x16x32_f16(a1, Wb[9],  r0, 0, 0, 0);
          r1 = __builtin_amdgcn_mfma_f32_16x16x32_f16(a1, Wb[11], r1, 0, 0, 0);
          r2 = __builtin_amdgcn_mfma_f32_16x16x32_f16(a1, Wb[13], r2, 0, 0, 0);
          r3 = __builtin_amdgcn_mfma_f32_16x16x32_f16(a1, Wb[15], r3, 0, 0, 0);
          const float sf01 = u1 ? r1[0] : r0[0];
          const float sf23 = u1 ? r3[0] : r2[0];
          const float df   = u2 ? sf23 : sf01;
          const float paf  = fmaf(x0, wxa[1], fmaf(x1, wxb[1], df + bb[1]));
          const float fg   = sigm(paf);

          c = fmaf(fg, c, ig * gg);
          h = og * tanh_(c);

          const int tt = hf * 64 + tl;
          slot[tt * HID + lane] = (__fp16)h;   // ds_write_b16 (ring, off chain)
        }
      }
      if (lane == 0)
        __hip_atomic_store(&prod, off + 1, __ATOMIC_RELEASE, __HIP_MEMORY_SCOPE_WORKGROUP);
    }
#undef OSTEP
  } else {
    // ================= loss wave =================
    const float wo   = W_out[lane];
    const float bout = b_out[0];
    const int   os   = open_slices[s];
    const float OL   = __logf(p[2 * os]) + __logf(p[2 * os + 1]);
    const float coef = open_probs[s] * (2.0f * ls_probs[s] - 1.0f);

    float S = 1.0f, D = 1.0f, lsum = 0.0f, psum = 0.0f;

    for (int off = 0; off < n_chunks; ++off) {
      const int cb = tbase + off * CH;
      const float2 cA = p2[cb + lane];
      const float2 cB = p2[cb + HID + lane];
      const float LA = __logf(cA.x) + __logf(cA.y);
      const float LB = __logf(cB.x) + __logf(cB.y);

      while (__hip_atomic_load(&prod, __ATOMIC_ACQUIRE, __HIP_MEMORY_SCOPE_WORKGROUP) <= off)
        __builtin_amdgcn_s_sleep(32);

      const __fp16* slot = &ring[off & 1][0][0];
#pragma unroll 1
      for (int tt = 0; tt < CH; ++tt) {
        const float hv = (float)slot[tt * HID + lane];
        const float z  = rlf(dpp_wave_sum(hv * wo), 63);
        const float pr = sigm(z + bout);
        const float Lt = (tt < 64) ? rlf(LA, tt) : rlf(LB, tt - 64);
        const float pn = (tt == 0) ? pr : pr * D;
        lsum = fmaf(pn, Lt, lsum);
        psum += pn;
        if (tt == 0)           D = S * (1.0f - pr);   // chunk t=0 undiscounted (ref quirk)
        else if (tt < CH - 1)  D *= (1.0f - pr);
        else                   S = D;                  // carry excludes (1-p_last)
      }
      if (lane == 0)
        __hip_atomic_store(&cons, off + 1, __ATOMIC_RELEASE, __HIP_MEMORY_SCOPE_WORKGROUP);
    }
    if (lane == 0) atomicAdd(out, coef * (lsum - OL * psum));
  }
}

extern "C" void kernel_launch(void* const* d_in, const int* in_sizes, int n_in,
                              void* d_out, int out_size, void* d_ws, size_t ws_size,
                              hipStream_t stream) {
  (void)hipMemsetAsync(d_out, 0, sizeof(float), stream);

  pc_lstm_kernel<<<dim3(1024), dim3(128), 0, stream>>>(
      (const int*)d_in[0],    // inds
      (const float*)d_in[1],  // p
      (const float*)d_in[2],  // ls_probs
      (const float*)d_in[3],  // open_probs
      (const int*)d_in[4],    // open_slices
      (const float*)d_in[5],  // open_hx
      (const float*)d_in[6],  // W_ih
      (const float*)d_in[7],  // W_hh
      (const float*)d_in[8],  // b_ih
      (const float*)d_in[9],  // b_hh
      (const float*)d_in[10], // W_out
      (const float*)d_in[11], // b_out
      (const int*)d_in[12],   // n_chunks
      (float*)d_out);
}

// Round 8
// 7252.853 us; speedup vs baseline: 1.4954x; 1.4015x over previous
//
#include <hip/hip_runtime.h>

// PositionCloser round 21: R15 (7031us champion) with the MFMA schedule
// software-pipelined. R20 post-mortem re-count: R15's VALUBusy INCLUDES MFMA
// (49.4 MFMA + ~4 true VALU); the remaining ~520 cyc/step is STALL, mostly
// from R15's adjacent dependent MFMA pairs (q=mfma(a0..); q=mfma(a1..,q) -
// C-in read ~16-24 cyc before producer D ready, x16 pairs ~300 cyc bubbles)
// plus the fully-exposed extract/transcendental tail (~150).
// Fix (identical math, reordered):
//  1) stage-split: 16 independent a0-stage MFMAs, then 16 a1-stage (C-in
//     arrives >=256 cyc after producer -> no stalls);
//  2) extracts/exp chains woven under a1-stage issue (i after tiles 0-7,
//     f after 8-11, g after 12-15); o-gate extracted LAST, under the
//     c -> tanh(c) chain that doesn't need it.
// Everything else byte-identical to R15 (absmax 0.0 proven).

#define CH  128
#define HID 64

typedef __fp16 half8 __attribute__((ext_vector_type(8)));
typedef float  f32x4 __attribute__((ext_vector_type(4)));
typedef int    int4v __attribute__((ext_vector_type(4)));

__device__ __forceinline__ float rlf(float v, int l) {
  return __builtin_bit_cast(float, __builtin_amdgcn_readlane(__builtin_bit_cast(int, v), l));
}
__device__ __forceinline__ int packh(float a, float b) {
  return __builtin_bit_cast(int, __builtin_amdgcn_cvt_pkrtz(a, b));
}
__device__ __forceinline__ float frcp(float x) { return __builtin_amdgcn_rcpf(x); }
__device__ __forceinline__ float sigm(float x) { return frcp(1.0f + __expf(-x)); }
__device__ __forceinline__ float tanh_(float x) {
  float e = __expf(2.0f * x);
  return 1.0f - 2.0f * frcp(e + 1.0f);
}
template <int CTRL, int RMASK>
__device__ __forceinline__ float dpp_add(float v) {
  int x = __builtin_amdgcn_update_dpp(0, __builtin_bit_cast(int, v), CTRL, RMASK, 0xF, true);
  return v + __builtin_bit_cast(float, x);
}
__device__ __forceinline__ float dpp_xor1(float v) {  // quad_perm [1,0,3,2]
  int x = __builtin_amdgcn_update_dpp(0, __builtin_bit_cast(int, v), 0xB1, 0xF, 0xF, true);
  return __builtin_bit_cast(float, x);
}
__device__ __forceinline__ float dpp_wave_sum(float v) {  // total lands in lane 63
  v = dpp_add<0x111, 0xF>(v);
  v = dpp_add<0x112, 0xF>(v);
  v = dpp_add<0x114, 0xF>(v);
  v = dpp_add<0x118, 0xF>(v);
  v = dpp_add<0x142, 0xA>(v);   // row_bcast:15
  v = dpp_add<0x143, 0xC>(v);   // row_bcast:31
  return v;
}

__global__ __attribute__((amdgpu_flat_work_group_size(128, 128), amdgpu_waves_per_eu(2, 2)))
void pc_lstm_kernel(const int* __restrict__ inds,
                    const float* __restrict__ p,
                    const float* __restrict__ ls_probs,
                    const float* __restrict__ open_probs,
                    const int* __restrict__ open_slices,
                    const float* __restrict__ open_hx,
                    const float* __restrict__ W_ih,
                    const float* __restrict__ W_hh,
                    const float* __restrict__ b_ih,
                    const float* __restrict__ b_hh,
                    const float* __restrict__ W_out,
                    const float* __restrict__ b_out,
                    const int* __restrict__ n_chunks_p,
                    float* __restrict__ out)
{
  __shared__ __fp16 ring[2][CH][HID];   // 32 KB: h history for the lagged loss
  __shared__ int prod;                  // chunks fully written by wave0
  __shared__ int cons;                  // chunks fully consumed by wave1

  const int tid  = threadIdx.x;
  const int wv   = tid >> 6;           // 0 = compute, 1 = loss
  const int lane = tid & 63;
  const int s    = blockIdx.x;         // one sequence per block
  const int n_chunks = n_chunks_p[0];
  const int tbase = inds[s >> 4] + (s & 15);
  const float2* p2 = (const float2*)p;

  if (tid == 0) { prod = 0; cons = 0; }
  __syncthreads();                      // only barrier in the kernel

  if (wv == 0) {
    // ================= compute wave =================
    const int kg = lane >> 4;          // k-group (A/B fragment k-chunk index)
    const int cc = lane & 15;          // column within a 16-wide N-tile

    // B fragments (HW-verified R15 packing): tile t covers preact rows
    // n = 16t + col; k = 32*kc + 8*kg + j. Gate g owns tiles 4g..4g+3.
    half8 Wb[32];
#pragma unroll
    for (int t = 0; t < 16; ++t) {
#pragma unroll
      for (int kc = 0; kc < 2; ++kc) {
        const float* wp = W_hh + (16 * t + cc) * HID + 32 * kc + 8 * kg;
        half8 w;
#pragma unroll
        for (int j = 0; j < 8; ++j) w[j] = (__fp16)wp[j];
        Wb[2 * t + kc] = w;
      }
    }

    float wxa[4], wxb[4], bb[4];
#pragma unroll
    for (int g = 0; g < 4; ++g) {
      const int r = g * HID + lane;
      wxa[g] = W_ih[2 * r];
      wxb[g] = W_ih[2 * r + 1];
      bb[g]  = b_ih[r] + b_hh[r];
    }
    float h = open_hx[(s * 2 + 0) * HID + lane];
    float c = open_hx[(s * 2 + 1) * HID + lane];

    // bpermute byte-indices (loop-invariant):
    // a0 word w pulls hp from lane 8*kg+2w; a1 from lane 32+8*kg+2w.
    int ia0[4], ia1[4];
#pragma unroll
    for (int w = 0; w < 4; ++w) {
      ia0[w] = 4 * (8 * kg + 2 * w);
      ia1[w] = 4 * (32 + 8 * kg + 2 * w);
    }

    const bool u1 = (lane & 16) != 0;  // bit0 of u = lane>>4
    const bool u2 = (lane & 32) != 0;  // bit1 of u
    const f32x4 zero4 = {0.f, 0.f, 0.f, 0.f};

    float2 curA = p2[tbase + lane];
    float2 curB = p2[tbase + HID + lane];
    float2 nxtA = curA, nxtB = curB;

    for (int off = 0; off < n_chunks; ++off) {
      if (off) { curA = nxtA; curB = nxtB; }
      const float px0 = rlf(curA.x, 0);
      const float px1 = rlf(curA.y, 0);
      float2 xA, xB;                       // pre-subtracted chunk base
      xA.x = curA.x - px0; xA.y = curA.y - px1;
      xB.x = curB.x - px0; xB.y = curB.y - px1;
      if (off + 1 < n_chunks) {
        const int nb = tbase + (off + 1) * CH;
        nxtA = p2[nb + lane];
        nxtB = p2[nb + HID + lane];
      }
      while (__hip_atomic_load(&cons, __ATOMIC_ACQUIRE, __HIP_MEMORY_SCOPE_WORKGROUP) + 2 <= off)
        __builtin_amdgcn_s_sleep(8);

      __fp16* slot = &ring[off & 1][0][0];
#pragma unroll
      for (int hf = 0; hf < 2; ++hf) {
        const float xcx = hf ? xB.x : xA.x;
        const float xcy = hf ? xB.y : xA.y;
#pragma unroll 1
        for (int tl = 0; tl < 64; ++tl) {
          // ---- head: packed h pairs -> 8 bperm (a0 first, then a1) ----
          const int hp = packh(h, dpp_xor1(h));   // even lane 2j: (h_2j, h_2j+1)
          int4v A0, A1;
#pragma unroll
          for (int w = 0; w < 4; ++w) A0[w] = __builtin_amdgcn_ds_bpermute(ia0[w], hp);
#pragma unroll
          for (int w = 0; w < 4; ++w) A1[w] = __builtin_amdgcn_ds_bpermute(ia1[w], hp);
          const half8 a0 = __builtin_bit_cast(half8, A0);   // k = 0..31
          const half8 a1 = __builtin_bit_cast(half8, A1);   // k = 32..63

          const float x0 = rlf(xcx, tl);
          const float x1 = rlf(xcy, tl);

          // ---- a0 stage: 16 independent MFMAs (no C-in dependencies) ----
          f32x4 t0  = __builtin_amdgcn_mfma_f32_16x16x32_f16(a0, Wb[0],  zero4, 0, 0, 0);
          f32x4 t1  = __builtin_amdgcn_mfma_f32_16x16x32_f16(a0, Wb[2],  zero4, 0, 0, 0);
          f32x4 t2  = __builtin_amdgcn_mfma_f32_16x16x32_f16(a0, Wb[4],  zero4, 0, 0, 0);
          f32x4 t3  = __builtin_amdgcn_mfma_f32_16x16x32_f16(a0, Wb[6],  zero4, 0, 0, 0);
          f32x4 t4  = __builtin_amdgcn_mfma_f32_16x16x32_f16(a0, Wb[8],  zero4, 0, 0, 0);
          f32x4 t5  = __builtin_amdgcn_mfma_f32_16x16x32_f16(a0, Wb[10], zero4, 0, 0, 0);
          f32x4 t6  = __builtin_amdgcn_mfma_f32_16x16x32_f16(a0, Wb[12], zero4, 0, 0, 0);
          f32x4 t7  = __builtin_amdgcn_mfma_f32_16x16x32_f16(a0, Wb[14], zero4, 0, 0, 0);
          f32x4 t8  = __builtin_amdgcn_mfma_f32_16x16x32_f16(a0, Wb[16], zero4, 0, 0, 0);
          f32x4 t9  = __builtin_amdgcn_mfma_f32_16x16x32_f16(a0, Wb[18], zero4, 0, 0, 0);
          f32x4 t10 = __builtin_amdgcn_mfma_f32_16x16x32_f16(a0, Wb[20], zero4, 0, 0, 0);
          f32x4 t11 = __builtin_amdgcn_mfma_f32_16x16x32_f16(a0, Wb[22], zero4, 0, 0, 0);
          f32x4 t12 = __builtin_amdgcn_mfma_f32_16x16x32_f16(a0, Wb[24], zero4, 0, 0, 0);
          f32x4 t13 = __builtin_amdgcn_mfma_f32_16x16x32_f16(a0, Wb[26], zero4, 0, 0, 0);
          f32x4 t14 = __builtin_amdgcn_mfma_f32_16x16x32_f16(a0, Wb[28], zero4, 0, 0, 0);
          f32x4 t15 = __builtin_amdgcn_mfma_f32_16x16x32_f16(a0, Wb[30], zero4, 0, 0, 0);

          // ---- a1 stage: C-in produced >=16 issues earlier -> no stalls ----
          t0  = __builtin_amdgcn_mfma_f32_16x16x32_f16(a1, Wb[1],  t0,  0, 0, 0);
          t1  = __builtin_amdgcn_mfma_f32_16x16x32_f16(a1, Wb[3],  t1,  0, 0, 0);
          t2  = __builtin_amdgcn_mfma_f32_16x16x32_f16(a1, Wb[5],  t2,  0, 0, 0);
          t3  = __builtin_amdgcn_mfma_f32_16x16x32_f16(a1, Wb[7],  t3,  0, 0, 0);
          t4  = __builtin_amdgcn_mfma_f32_16x16x32_f16(a1, Wb[9],  t4,  0, 0, 0);
          t5  = __builtin_amdgcn_mfma_f32_16x16x32_f16(a1, Wb[11], t5,  0, 0, 0);
          t6  = __builtin_amdgcn_mfma_f32_16x16x32_f16(a1, Wb[13], t6,  0, 0, 0);
          t7  = __builtin_amdgcn_mfma_f32_16x16x32_f16(a1, Wb[15], t7,  0, 0, 0);

          // i-gate extract (t0..t3 ready: produced 8+ MFMA-issues ago)
          const float si01 = u1 ? t1[0] : t0[0];
          const float si23 = u1 ? t3[0] : t2[0];
          const float di   = u2 ? si23 : si01;
          const float pai  = fmaf(x0, wxa[0], fmaf(x1, wxb[0], di + bb[0]));
          const float ei   = __expf(-pai);

          t8  = __builtin_amdgcn_mfma_f32_16x16x32_f16(a1, Wb[17], t8,  0, 0, 0);
          t9  = __builtin_amdgcn_mfma_f32_16x16x32_f16(a1, Wb[19], t9,  0, 0, 0);
          t10 = __builtin_amdgcn_mfma_f32_16x16x32_f16(a1, Wb[21], t10, 0, 0, 0);
          t11 = __builtin_amdgcn_mfma_f32_16x16x32_f16(a1, Wb[23], t11, 0, 0, 0);

          // f-gate extract (t4..t7)
          const float sf01 = u1 ? t5[0] : t4[0];
          const float sf23 = u1 ? t7[0] : t6[0];
          const float df   = u2 ? sf23 : sf01;
          const float paf  = fmaf(x0, wxa[1], fmaf(x1, wxb[1], df + bb[1]));
          const float ef   = __expf(-paf);

          t12 = __builtin_amdgcn_mfma_f32_16x16x32_f16(a1, Wb[25], t12, 0, 0, 0);
          t13 = __builtin_amdgcn_mfma_f32_16x16x32_f16(a1, Wb[27], t13, 0, 0, 0);
          t14 = __builtin_amdgcn_mfma_f32_16x16x32_f16(a1, Wb[29], t14, 0, 0, 0);
          t15 = __builtin_amdgcn_mfma_f32_16x16x32_f16(a1, Wb[31], t15, 0, 0, 0);

          // g-gate extract (t8..t11) + gate math; o-tiles (t12..t15) drain
          const float sg01 = u1 ? t9[0]  : t8[0];
          const float sg23 = u1 ? t11[0] : t10[0];
          const float dg   = u2 ? sg23 : sg01;
          const float pag  = fmaf(x0, wxa[2], fmaf(x1, wxb[2], dg + bb[2]));
          const float eg   = __expf(2.0f * pag);

          const float ig = frcp(1.0f + ei);
          const float fg = frcp(1.0f + ef);
          const float gg = 1.0f - 2.0f * frcp(eg + 1.0f);
          c = fmaf(fg, c, ig * gg);
          const float tc = tanh_(c);

          // o-gate extract LAST, under the c/tanh chain
          const float so01 = u1 ? t13[0] : t12[0];
          const float so23 = u1 ? t15[0] : t14[0];
          const float dox  = u2 ? so23 : so01;
          const float pao  = fmaf(x0, wxa[3], fmaf(x1, wxb[3], dox + bb[3]));
          const float og   = sigm(pao);

          h = og * tc;

          const int tt = hf * 64 + tl;
          slot[tt * HID + lane] = (__fp16)h;   // ds_write_b16 (ring, off chain)
        }
      }
      if (lane == 0)
        __hip_atomic_store(&prod, off + 1, __ATOMIC_RELEASE, __HIP_MEMORY_SCOPE_WORKGROUP);
    }
  } else {
    // ================= loss wave =================
    const float wo   = W_out[lane];
    const float bout = b_out[0];
    const int   os   = open_slices[s];
    const float OL   = __logf(p[2 * os]) + __logf(p[2 * os + 1]);
    const float coef = open_probs[s] * (2.0f * ls_probs[s] - 1.0f);

    float S = 1.0f, D = 1.0f, lsum = 0.0f, psum = 0.0f;

    for (int off = 0; off < n_chunks; ++off) {
      const int cb = tbase + off * CH;
      const float2 cA = p2[cb + lane];
      const float2 cB = p2[cb + HID + lane];
      const float LA = __logf(cA.x) + __logf(cA.y);
      const float LB = __logf(cB.x) + __logf(cB.y);

      while (__hip_atomic_load(&prod, __ATOMIC_ACQUIRE, __HIP_MEMORY_SCOPE_WORKGROUP) <= off)
        __builtin_amdgcn_s_sleep(32);

      const __fp16* slot = &ring[off & 1][0][0];
#pragma unroll 1
      for (int tt = 0; tt < CH; ++tt) {
        const float hv = (float)slot[tt * HID + lane];
        const float z  = rlf(dpp_wave_sum(hv * wo), 63);
        const float pr = sigm(z + bout);
        const float Lt = (tt < 64) ? rlf(LA, tt) : rlf(LB, tt - 64);
        const float pn = (tt == 0) ? pr : pr * D;
        lsum = fmaf(pn, Lt, lsum);
        psum += pn;
        if (tt == 0)           D = S * (1.0f - pr);   // chunk t=0 undiscounted (ref quirk)
        else if (tt < CH - 1)  D *= (1.0f - pr);
        else                   S = D;                  // carry excludes (1-p_last)
      }
      if (lane == 0)
        __hip_atomic_store(&cons, off + 1, __ATOMIC_RELEASE, __HIP_MEMORY_SCOPE_WORKGROUP);
    }
    if (lane == 0) atomicAdd(out, coef * (lsum - OL * psum));
  }
}

extern "C" void kernel_launch(void* const* d_in, const int* in_sizes, int n_in,
                              void* d_out, int out_size, void* d_ws, size_t ws_size,
                              hipStream_t stream) {
  (void)hipMemsetAsync(d_out, 0, sizeof(float), stream);

  pc_lstm_kernel<<<dim3(1024), dim3(128), 0, stream>>>(
      (const int*)d_in[0],    // inds
      (const float*)d_in[1],  // p
      (const float*)d_in[2],  // ls_probs
      (const float*)d_in[3],  // open_probs
      (const int*)d_in[4],    // open_slices
      (const float*)d_in[5],  // open_hx
      (const float*)d_in[6],  // W_ih
      (const float*)d_in[7],  // W_hh
      (const float*)d_in[8],  // b_ih
      (const float*)d_in[9],  // b_hh
      (const float*)d_in[10], // W_out
      (const float*)d_in[11], // b_out
      (const int*)d_in[12],   // n_chunks
      (float*)d_out);
}

// Round 9
// 7189.416 us; speedup vs baseline: 1.5086x; 1.0088x over previous
//
#include <hip/hip_runtime.h>

// PositionCloser round 22: R21's stage-split ENFORCED with sched_barrier(0).
// R21 post-mortem: identical perf AND identical VGPR_Count(116) to R15 ->
// the compiler re-paired the a0/a1 MFMAs adjacently (pressure heuristic;
// 16 live acc quads don't fit the 256-reg/wave budget at 2 waves/SIMD).
// Pair-stall arithmetic: step 1030 = 512 MFMA-issue (48% MfmaUtil exact,
// 16cyc/MFMA) + ~256 pair-stall (latency~32 > issue 16) + ~250 head/tail.
// Fix: distance-2 interleave pinned by __builtin_amdgcn_sched_barrier(0)
// fences: region k = {a1 of pair k-1, a0 of pair k, extract VALU}. Dependent
// C-in arrives 2 issue slots (32cyc) after its producer -> no stall, and
// only ~2 pairs of accs live (+8 regs, fits). Per-gate extracts split into
// per-pair halves one region after the pair completes. Math byte-identical
// to R15/R21 (absmax 0.0 proven). Shell/sync/loss = R15.

#define CH  128
#define HID 64

typedef __fp16 half8 __attribute__((ext_vector_type(8)));
typedef float  f32x4 __attribute__((ext_vector_type(4)));
typedef int    int4v __attribute__((ext_vector_type(4)));

#define SB() __builtin_amdgcn_sched_barrier(0)
#define MFMA16(A, B, C) __builtin_amdgcn_mfma_f32_16x16x32_f16((A), (B), (C), 0, 0, 0)

__device__ __forceinline__ float rlf(float v, int l) {
  return __builtin_bit_cast(float, __builtin_amdgcn_readlane(__builtin_bit_cast(int, v), l));
}
__device__ __forceinline__ int packh(float a, float b) {
  return __builtin_bit_cast(int, __builtin_amdgcn_cvt_pkrtz(a, b));
}
__device__ __forceinline__ float frcp(float x) { return __builtin_amdgcn_rcpf(x); }
__device__ __forceinline__ float sigm(float x) { return frcp(1.0f + __expf(-x)); }
__device__ __forceinline__ float tanh_(float x) {
  float e = __expf(2.0f * x);
  return 1.0f - 2.0f * frcp(e + 1.0f);
}
template <int CTRL, int RMASK>
__device__ __forceinline__ float dpp_add(float v) {
  int x = __builtin_amdgcn_update_dpp(0, __builtin_bit_cast(int, v), CTRL, RMASK, 0xF, true);
  return v + __builtin_bit_cast(float, x);
}
__device__ __forceinline__ float dpp_xor1(float v) {  // quad_perm [1,0,3,2]
  int x = __builtin_amdgcn_update_dpp(0, __builtin_bit_cast(int, v), 0xB1, 0xF, 0xF, true);
  return __builtin_bit_cast(float, x);
}
__device__ __forceinline__ float dpp_wave_sum(float v) {  // total lands in lane 63
  v = dpp_add<0x111, 0xF>(v);
  v = dpp_add<0x112, 0xF>(v);
  v = dpp_add<0x114, 0xF>(v);
  v = dpp_add<0x118, 0xF>(v);
  v = dpp_add<0x142, 0xA>(v);   // row_bcast:15
  v = dpp_add<0x143, 0xC>(v);   // row_bcast:31
  return v;
}

__global__ __attribute__((amdgpu_flat_work_group_size(128, 128), amdgpu_waves_per_eu(2, 2)))
void pc_lstm_kernel(const int* __restrict__ inds,
                    const float* __restrict__ p,
                    const float* __restrict__ ls_probs,
                    const float* __restrict__ open_probs,
                    const int* __restrict__ open_slices,
                    const float* __restrict__ open_hx,
                    const float* __restrict__ W_ih,
                    const float* __restrict__ W_hh,
                    const float* __restrict__ b_ih,
                    const float* __restrict__ b_hh,
                    const float* __restrict__ W_out,
                    const float* __restrict__ b_out,
                    const int* __restrict__ n_chunks_p,
                    float* __restrict__ out)
{
  __shared__ __fp16 ring[2][CH][HID];   // 32 KB: h history for the lagged loss
  __shared__ int prod;                  // chunks fully written by wave0
  __shared__ int cons;                  // chunks fully consumed by wave1

  const int tid  = threadIdx.x;
  const int wv   = tid >> 6;           // 0 = compute, 1 = loss
  const int lane = tid & 63;
  const int s    = blockIdx.x;         // one sequence per block
  const int n_chunks = n_chunks_p[0];
  const int tbase = inds[s >> 4] + (s & 15);
  const float2* p2 = (const float2*)p;

  if (tid == 0) { prod = 0; cons = 0; }
  __syncthreads();                      // only barrier in the kernel

  if (wv == 0) {
    // ================= compute wave =================
    const int kg = lane >> 4;          // k-group (A/B fragment k-chunk index)
    const int cc = lane & 15;          // column within a 16-wide N-tile

    // B fragments (HW-verified R15 packing): tile t covers preact rows
    // n = 16t + col; k = 32*kc + 8*kg + j. Gate g owns tiles 4g..4g+3.
    half8 Wb[32];
#pragma unroll
    for (int t = 0; t < 16; ++t) {
#pragma unroll
      for (int kc = 0; kc < 2; ++kc) {
        const float* wp = W_hh + (16 * t + cc) * HID + 32 * kc + 8 * kg;
        half8 w;
#pragma unroll
        for (int j = 0; j < 8; ++j) w[j] = (__fp16)wp[j];
        Wb[2 * t + kc] = w;
      }
    }

    float wxa[4], wxb[4], bb[4];
#pragma unroll
    for (int g = 0; g < 4; ++g) {
      const int r = g * HID + lane;
      wxa[g] = W_ih[2 * r];
      wxb[g] = W_ih[2 * r + 1];
      bb[g]  = b_ih[r] + b_hh[r];
    }
    float h = open_hx[(s * 2 + 0) * HID + lane];
    float c = open_hx[(s * 2 + 1) * HID + lane];

    // bpermute byte-indices (loop-invariant):
    // a0 word w pulls hp from lane 8*kg+2w; a1 from lane 32+8*kg+2w.
    int ia0[4], ia1[4];
#pragma unroll
    for (int w = 0; w < 4; ++w) {
      ia0[w] = 4 * (8 * kg + 2 * w);
      ia1[w] = 4 * (32 + 8 * kg + 2 * w);
    }

    const bool u1 = (lane & 16) != 0;  // bit0 of u = lane>>4
    const bool u2 = (lane & 32) != 0;  // bit1 of u
    const f32x4 zero4 = {0.f, 0.f, 0.f, 0.f};

    float2 curA = p2[tbase + lane];
    float2 curB = p2[tbase + HID + lane];
    float2 nxtA = curA, nxtB = curB;

    for (int off = 0; off < n_chunks; ++off) {
      if (off) { curA = nxtA; curB = nxtB; }
      const float px0 = rlf(curA.x, 0);
      const float px1 = rlf(curA.y, 0);
      float2 xA, xB;                       // pre-subtracted chunk base
      xA.x = curA.x - px0; xA.y = curA.y - px1;
      xB.x = curB.x - px0; xB.y = curB.y - px1;
      if (off + 1 < n_chunks) {
        const int nb = tbase + (off + 1) * CH;
        nxtA = p2[nb + lane];
        nxtB = p2[nb + HID + lane];
      }
      while (__hip_atomic_load(&cons, __ATOMIC_ACQUIRE, __HIP_MEMORY_SCOPE_WORKGROUP) + 2 <= off)
        __builtin_amdgcn_s_sleep(8);

      __fp16* slot = &ring[off & 1][0][0];
#pragma unroll
      for (int hf = 0; hf < 2; ++hf) {
        const float xcx = hf ? xB.x : xA.x;
        const float xcy = hf ? xB.y : xA.y;
#pragma unroll 1
        for (int tl = 0; tl < 64; ++tl) {
          // ---- R0: head + a0 of pair0 ----
          const int hp = packh(h, dpp_xor1(h));   // even lane 2j: (h_2j, h_2j+1)
          int4v A0, A1;
#pragma unroll
          for (int w = 0; w < 4; ++w) A0[w] = __builtin_amdgcn_ds_bpermute(ia0[w], hp);
#pragma unroll
          for (int w = 0; w < 4; ++w) A1[w] = __builtin_amdgcn_ds_bpermute(ia1[w], hp);
          const half8 a0 = __builtin_bit_cast(half8, A0);   // k = 0..31
          const half8 a1 = __builtin_bit_cast(half8, A1);   // k = 32..63
          const float x0 = rlf(xcx, tl);
          const float x1 = rlf(xcy, tl);

          f32x4 t0 = MFMA16(a0, Wb[0], zero4);
          f32x4 t1 = MFMA16(a0, Wb[2], zero4);
          SB();
          // ---- R1: a1 p0 + a0 p1 ----
          t0 = MFMA16(a1, Wb[1], t0);
          t1 = MFMA16(a1, Wb[3], t1);
          f32x4 t2 = MFMA16(a0, Wb[4], zero4);
          f32x4 t3 = MFMA16(a0, Wb[6], zero4);
          SB();
          // ---- R2: a1 p1 + a0 p2 + i-extract half ----
          t2 = MFMA16(a1, Wb[5], t2);
          t3 = MFMA16(a1, Wb[7], t3);
          f32x4 t4 = MFMA16(a0, Wb[8],  zero4);
          f32x4 t5 = MFMA16(a0, Wb[10], zero4);
          const float si01 = u1 ? t1[0] : t0[0];
          SB();
          // ---- R3: a1 p2 + a0 p3 + i finish ----
          t4 = MFMA16(a1, Wb[9],  t4);
          t5 = MFMA16(a1, Wb[11], t5);
          f32x4 t6 = MFMA16(a0, Wb[12], zero4);
          f32x4 t7 = MFMA16(a0, Wb[14], zero4);
          const float si23 = u1 ? t3[0] : t2[0];
          const float di   = u2 ? si23 : si01;
          const float pai  = fmaf(x0, wxa[0], fmaf(x1, wxb[0], di + bb[0]));
          const float ei   = __expf(-pai);
          SB();
          // ---- R4: a1 p3 + a0 p4 + f-extract half ----
          t6 = MFMA16(a1, Wb[13], t6);
          t7 = MFMA16(a1, Wb[15], t7);
          f32x4 t8 = MFMA16(a0, Wb[16], zero4);
          f32x4 t9 = MFMA16(a0, Wb[18], zero4);
          const float sf01 = u1 ? t5[0] : t4[0];
          SB();
          // ---- R5: a1 p4 + a0 p5 + f finish ----
          t8 = MFMA16(a1, Wb[17], t8);
          t9 = MFMA16(a1, Wb[19], t9);
          f32x4 t10 = MFMA16(a0, Wb[20], zero4);
          f32x4 t11 = MFMA16(a0, Wb[22], zero4);
          const float sf23 = u1 ? t7[0] : t6[0];
          const float df   = u2 ? sf23 : sf01;
          const float paf  = fmaf(x0, wxa[1], fmaf(x1, wxb[1], df + bb[1]));
          const float ef   = __expf(-paf);
          SB();
          // ---- R6: a1 p5 + a0 p6 + g-extract half ----
          t10 = MFMA16(a1, Wb[21], t10);
          t11 = MFMA16(a1, Wb[23], t11);
          f32x4 t12 = MFMA16(a0, Wb[24], zero4);
          f32x4 t13 = MFMA16(a0, Wb[26], zero4);
          const float sg01 = u1 ? t9[0] : t8[0];
          SB();
          // ---- R7: a1 p6 + a0 p7 + g finish + c-chain ----
          t12 = MFMA16(a1, Wb[25], t12);
          t13 = MFMA16(a1, Wb[27], t13);
          f32x4 t14 = MFMA16(a0, Wb[28], zero4);
          f32x4 t15 = MFMA16(a0, Wb[30], zero4);
          const float sg23 = u1 ? t11[0] : t10[0];
          const float dg   = u2 ? sg23 : sg01;
          const float pag  = fmaf(x0, wxa[2], fmaf(x1, wxb[2], dg + bb[2]));
          const float eg   = __expf(2.0f * pag);
          const float ig = frcp(1.0f + ei);
          const float fg = frcp(1.0f + ef);
          const float gg = 1.0f - 2.0f * frcp(eg + 1.0f);
          c = fmaf(fg, c, ig * gg);
          SB();
          // ---- R8: a1 p7 + tanh(c) + o-extract half ----
          t14 = MFMA16(a1, Wb[29], t14);
          t15 = MFMA16(a1, Wb[31], t15);
          const float tc   = tanh_(c);
          const float so01 = u1 ? t13[0] : t12[0];
          SB();
          // ---- tail: o finish + h + ring write ----
          const float so23 = u1 ? t15[0] : t14[0];
          const float dox  = u2 ? so23 : so01;
          const float pao  = fmaf(x0, wxa[3], fmaf(x1, wxb[3], dox + bb[3]));
          const float og   = sigm(pao);
          h = og * tc;

          const int tt = hf * 64 + tl;
          slot[tt * HID + lane] = (__fp16)h;   // ds_write_b16 (ring, off chain)
        }
      }
      if (lane == 0)
        __hip_atomic_store(&prod, off + 1, __ATOMIC_RELEASE, __HIP_MEMORY_SCOPE_WORKGROUP);
    }
  } else {
    // ================= loss wave =================
    const float wo   = W_out[lane];
    const float bout = b_out[0];
    const int   os   = open_slices[s];
    const float OL   = __logf(p[2 * os]) + __logf(p[2 * os + 1]);
    const float coef = open_probs[s] * (2.0f * ls_probs[s] - 1.0f);

    float S = 1.0f, D = 1.0f, lsum = 0.0f, psum = 0.0f;

    for (int off = 0; off < n_chunks; ++off) {
      const int cb = tbase + off * CH;
      const float2 cA = p2[cb + lane];
      const float2 cB = p2[cb + HID + lane];
      const float LA = __logf(cA.x) + __logf(cA.y);
      const float LB = __logf(cB.x) + __logf(cB.y);

      while (__hip_atomic_load(&prod, __ATOMIC_ACQUIRE, __HIP_MEMORY_SCOPE_WORKGROUP) <= off)
        __builtin_amdgcn_s_sleep(32);

      const __fp16* slot = &ring[off & 1][0][0];
#pragma unroll 1
      for (int tt = 0; tt < CH; ++tt) {
        const float hv = (float)slot[tt * HID + lane];
        const float z  = rlf(dpp_wave_sum(hv * wo), 63);
        const float pr = sigm(z + bout);
        const float Lt = (tt < 64) ? rlf(LA, tt) : rlf(LB, tt - 64);
        const float pn = (tt == 0) ? pr : pr * D;
        lsum = fmaf(pn, Lt, lsum);
        psum += pn;
        if (tt == 0)           D = S * (1.0f - pr);   // chunk t=0 undiscounted (ref quirk)
        else if (tt < CH - 1)  D *= (1.0f - pr);
        else                   S = D;                  // carry excludes (1-p_last)
      }
      if (lane == 0)
        __hip_atomic_store(&cons, off + 1, __ATOMIC_RELEASE, __HIP_MEMORY_SCOPE_WORKGROUP);
    }
    if (lane == 0) atomicAdd(out, coef * (lsum - OL * psum));
  }
}

extern "C" void kernel_launch(void* const* d_in, const int* in_sizes, int n_in,
                              void* d_out, int out_size, void* d_ws, size_t ws_size,
                              hipStream_t stream) {
  (void)hipMemsetAsync(d_out, 0, sizeof(float), stream);

  pc_lstm_kernel<<<dim3(1024), dim3(128), 0, stream>>>(
      (const int*)d_in[0],    // inds
      (const float*)d_in[1],  // p
      (const float*)d_in[2],  // ls_probs
      (const float*)d_in[3],  // open_probs
      (const int*)d_in[4],    // open_slices
      (const float*)d_in[5],  // open_hx
      (const float*)d_in[6],  // W_ih
      (const float*)d_in[7],  // W_hh
      (const float*)d_in[8],  // b_ih
      (const float*)d_in[9],  // b_hh
      (const float*)d_in[10], // W_out
      (const float*)d_in[11], // b_out
      (const int*)d_in[12],   // n_chunks
      (float*)d_out);
}